// Round 1
// baseline (49.746 us; speedup 1.0000x reference)
//
#include <hip/hip_runtime.h>

// HungarianMatcher batched cost matrix.
// B=64, Q=900, T=300, C=80. out[b][q][t] f32.
// cost = 5*L1(bbox) + 2*(focal pos-neg on p=sigmoid(logit[label])) - 2*giou

constexpr int B = 64, Q = 900, T = 300, C = 80;
constexpr int QTILE = 10;           // 900 % 10 == 0
constexpr int BLOCK = 256;
constexpr float ALPHA = 0.25f;
constexpr float EPSF  = 1e-8f;

__global__ __launch_bounds__(BLOCK) void matcher_cost_kernel(
    const float* __restrict__ logits,   // [B,Q,C]
    const float* __restrict__ pboxes,   // [B,Q,4] cxcywh
    const int*   __restrict__ tlabels,  // [B,T]
    const float* __restrict__ tboxes,   // [B,T,4] cxcywh
    float* __restrict__ out)            // [B,Q,T]
{
    // Target SoA (conflict-free stride-1 by t)
    __shared__ float s_tcx[T], s_tcy[T], s_tw[T], s_th[T];
    __shared__ float s_tx0[T], s_ty0[T], s_tx1[T], s_ty1[T], s_ta[T];
    __shared__ int   s_tl[T];
    // Per-q focal class-cost table and pred-box data
    __shared__ float s_cls[QTILE * C];
    __shared__ float s_p[QTILE][9];     // cx,cy,w,h,x0,y0,x1,y1,area

    const int bid = blockIdx.x;
    const int b   = bid / (Q / QTILE);
    const int q0  = (bid % (Q / QTILE)) * QTILE;
    const int tid = threadIdx.x;

    // ---- stage targets ----
    for (int t = tid; t < T; t += BLOCK) {
        float4 bx = *(const float4*)(tboxes + ((size_t)b * T + t) * 4);
        s_tcx[t] = bx.x; s_tcy[t] = bx.y; s_tw[t] = bx.z; s_th[t] = bx.w;
        float x0 = bx.x - 0.5f * bx.z, y0 = bx.y - 0.5f * bx.w;
        float x1 = bx.x + 0.5f * bx.z, y1 = bx.y + 0.5f * bx.w;
        s_tx0[t] = x0; s_ty0[t] = y0; s_tx1[t] = x1; s_ty1[t] = y1;
        s_ta[t]  = (x1 - x0) * (y1 - y0);
        s_tl[t]  = tlabels[(size_t)b * T + t];
    }

    // ---- stage pred boxes for this q-tile ----
    if (tid < QTILE) {
        float4 bx = *(const float4*)(pboxes + ((size_t)b * Q + q0 + tid) * 4);
        float x0 = bx.x - 0.5f * bx.z, y0 = bx.y - 0.5f * bx.w;
        float x1 = bx.x + 0.5f * bx.z, y1 = bx.y + 0.5f * bx.w;
        s_p[tid][0] = bx.x; s_p[tid][1] = bx.y; s_p[tid][2] = bx.z; s_p[tid][3] = bx.w;
        s_p[tid][4] = x0;   s_p[tid][5] = y0;   s_p[tid][6] = x1;   s_p[tid][7] = y1;
        s_p[tid][8] = (x1 - x0) * (y1 - y0);
    }

    // ---- focal class-cost table: one entry per (q_local, class) ----
    for (int i = tid; i < QTILE * C; i += BLOCK) {
        int ql = i / C;
        int c  = i - ql * C;
        float x  = logits[((size_t)b * Q + q0 + ql) * C + c];
        float pr = 1.0f / (1.0f + __expf(-x));
        float om = 1.0f - pr;
        float pos = ALPHA * om * om * (-__logf(pr + EPSF));
        float neg = (1.0f - ALPHA) * pr * pr * (-__logf(om + EPSF));
        s_cls[i] = pos - neg;
    }

    __syncthreads();

    // ---- main: QTILE*T contiguous outputs for this block ----
    float* outb = out + (size_t)b * Q * T + (size_t)q0 * T;
    for (int e = tid; e < QTILE * T; e += BLOCK) {
        int ql = e / T;
        int t  = e - ql * T;

        float pcx = s_p[ql][0], pcy = s_p[ql][1], pw = s_p[ql][2], ph = s_p[ql][3];
        float px0 = s_p[ql][4], py0 = s_p[ql][5], px1 = s_p[ql][6], py1 = s_p[ql][7];
        float pa  = s_p[ql][8];

        float tcx = s_tcx[t], tcy = s_tcy[t], tw = s_tw[t], th = s_th[t];
        float tx0 = s_tx0[t], ty0 = s_ty0[t], tx1 = s_tx1[t], ty1 = s_ty1[t];
        float ta  = s_ta[t];

        // L1 bbox cost (cxcywh space)
        float cbbox = fabsf(pcx - tcx) + fabsf(pcy - tcy) +
                      fabsf(pw  - tw ) + fabsf(ph  - th );

        // class cost gather
        float ccls = s_cls[ql * C + s_tl[t]];

        // GIoU
        float ix0 = fmaxf(px0, tx0), iy0 = fmaxf(py0, ty0);
        float ix1 = fminf(px1, tx1), iy1 = fminf(py1, ty1);
        float iw  = fmaxf(ix1 - ix0, 0.0f);
        float ih  = fmaxf(iy1 - iy0, 0.0f);
        float inter = iw * ih;
        float uni   = pa + ta - inter;
        float iou   = inter / uni;
        float cx0 = fminf(px0, tx0), cy0 = fminf(py0, ty0);
        float cx1 = fmaxf(px1, tx1), cy1 = fmaxf(py1, ty1);
        float cw  = fmaxf(cx1 - cx0, 0.0f);
        float chh = fmaxf(cy1 - cy0, 0.0f);
        float ca  = cw * chh;
        float giou = iou - (ca - uni) / ca;

        float cost = 5.0f * cbbox + 2.0f * ccls - 2.0f * giou;

        // nan_to_num(nan=1.0, posinf=1e6, neginf=-1e6)
        if (cost != cost) cost = 1.0f;
        else cost = fminf(fmaxf(cost, -1.0e6f), 1.0e6f);

        outb[e] = cost;   // e == ql*T + t: contiguous & coalesced
    }
}

extern "C" void kernel_launch(void* const* d_in, const int* in_sizes, int n_in,
                              void* d_out, int out_size, void* d_ws, size_t ws_size,
                              hipStream_t stream) {
    const float* logits  = (const float*)d_in[0];  // [B,Q,C]
    const float* pboxes  = (const float*)d_in[1];  // [B,Q,4]
    const int*   tlabels = (const int*)  d_in[2];  // [B,T]
    const float* tboxes  = (const float*)d_in[3];  // [B,T,4]
    float* out = (float*)d_out;                    // [B,Q,T]

    dim3 grid(B * (Q / QTILE));
    dim3 block(BLOCK);
    matcher_cost_kernel<<<grid, block, 0, stream>>>(logits, pboxes, tlabels, tboxes, out);
}

// Round 2
// 35.387 us; speedup vs baseline: 1.4058x; 1.4058x over previous
//
#include <hip/hip_runtime.h>

// HungarianMatcher batched cost matrix.
// B=64, Q=900, T=300, C=80. out[b][q][t] f32.
// cost = 5*L1(bbox) + 2*(focal pos-neg on p=sigmoid(logit[label])) - 2*giou
//
// R2: t-vectorized by 4 (float4 LDS reads + float4 stores), v_rcp_f32
// instead of IEEE div, per-group integer div. Main loop is VALU-bound;
// target ~1.6 cy/elem/SIMD.

constexpr int B = 64, Q = 900, T = 300, C = 80;
constexpr int QTILE = 10;            // 900 % 10 == 0
constexpr int BLOCK = 256;
constexpr int TG    = T / 4;         // 75 t-groups of 4
constexpr int NG    = QTILE * TG;    // 750 groups per block
constexpr float ALPHA = 0.25f;
constexpr float EPSF  = 1e-8f;

__device__ __forceinline__ float fast_rcp(float x) {
    return __builtin_amdgcn_rcpf(x);   // v_rcp_f32, ~1 ulp
}

__global__ __launch_bounds__(BLOCK) void matcher_cost_kernel(
    const float* __restrict__ logits,   // [B,Q,C]
    const float* __restrict__ pboxes,   // [B,Q,4] cxcywh
    const int*   __restrict__ tlabels,  // [B,T]
    const float* __restrict__ tboxes,   // [B,T,4] cxcywh
    float* __restrict__ out)            // [B,Q,T]
{
    // Target SoA as float4-per-4t: fields cx,cy,w,h,x0,y0,x1,y1,area
    __shared__ float4 s_t[9][TG];
    __shared__ int4   s_tl[TG];
    __shared__ float  s_cls[QTILE * C];
    __shared__ float4 s_p[QTILE][3];    // {cx,cy,w,h},{x0,y0,x1,y1},{area,-,-,-}

    const int bid = blockIdx.x;
    const int b   = bid / (Q / QTILE);
    const int q0  = (bid % (Q / QTILE)) * QTILE;
    const int tid = threadIdx.x;

    // ---- stage targets (scalar writes into float4 SoA) ----
    for (int t = tid; t < T; t += BLOCK) {
        float4 bx = *(const float4*)(tboxes + ((size_t)b * T + t) * 4);
        float x0 = bx.x - 0.5f * bx.z, y0 = bx.y - 0.5f * bx.w;
        float x1 = bx.x + 0.5f * bx.z, y1 = bx.y + 0.5f * bx.w;
        ((float*)&s_t[0][0])[t] = bx.x;
        ((float*)&s_t[1][0])[t] = bx.y;
        ((float*)&s_t[2][0])[t] = bx.z;
        ((float*)&s_t[3][0])[t] = bx.w;
        ((float*)&s_t[4][0])[t] = x0;
        ((float*)&s_t[5][0])[t] = y0;
        ((float*)&s_t[6][0])[t] = x1;
        ((float*)&s_t[7][0])[t] = y1;
        ((float*)&s_t[8][0])[t] = (x1 - x0) * (y1 - y0);
        ((int*)&s_tl[0])[t]     = tlabels[(size_t)b * T + t];
    }

    // ---- stage pred boxes for this q-tile ----
    if (tid < QTILE) {
        float4 bx = *(const float4*)(pboxes + ((size_t)b * Q + q0 + tid) * 4);
        float x0 = bx.x - 0.5f * bx.z, y0 = bx.y - 0.5f * bx.w;
        float x1 = bx.x + 0.5f * bx.z, y1 = bx.y + 0.5f * bx.w;
        s_p[tid][0] = make_float4(bx.x, bx.y, bx.z, bx.w);
        s_p[tid][1] = make_float4(x0, y0, x1, y1);
        s_p[tid][2] = make_float4((x1 - x0) * (y1 - y0), 0.f, 0.f, 0.f);
    }

    // ---- focal class-cost table, float4-vectorized (QTILE*C = 800) ----
    {
        const float* lg = logits + ((size_t)b * Q + q0) * C;  // 800 contiguous
        for (int i4 = tid; i4 < QTILE * C / 4; i4 += BLOCK) {
            float4 x = *(const float4*)(lg + i4 * 4);
            float4 r;
            #pragma unroll
            for (int k = 0; k < 4; ++k) {
                float xv = (&x.x)[k];
                float pr = fast_rcp(1.0f + __expf(-xv));
                float om = 1.0f - pr;
                float pos = ALPHA * om * om * (-__logf(pr + EPSF));
                float neg = (1.0f - ALPHA) * pr * pr * (-__logf(om + EPSF));
                (&r.x)[k] = pos - neg;
            }
            *(float4*)(s_cls + i4 * 4) = r;
        }
    }

    __syncthreads();

    // ---- main: NG groups of 4 consecutive t; contiguous float4 stores ----
    float* outb = out + ((size_t)b * Q + q0) * T;
    for (unsigned g = tid; g < NG; g += BLOCK) {
        unsigned ql = g / TG;            // magic-mul div by 75
        unsigned tg = g - ql * TG;

        float4 p0 = s_p[ql][0];          // cx,cy,w,h
        float4 p1 = s_p[ql][1];          // x0,y0,x1,y1
        float  pa = s_p[ql][2].x;
        const float* clsrow = s_cls + ql * C;

        float4 tcx = s_t[0][tg], tcy = s_t[1][tg];
        float4 tw  = s_t[2][tg], th  = s_t[3][tg];
        float4 tx0 = s_t[4][tg], ty0 = s_t[5][tg];
        float4 tx1 = s_t[6][tg], ty1 = s_t[7][tg];
        float4 ta  = s_t[8][tg];
        int4   lab = s_tl[tg];

        float4 res;
        #pragma unroll
        for (int k = 0; k < 4; ++k) {
            float tcx_ = (&tcx.x)[k], tcy_ = (&tcy.x)[k];
            float tw_  = (&tw.x)[k],  th_  = (&th.x)[k];
            float tx0_ = (&tx0.x)[k], ty0_ = (&ty0.x)[k];
            float tx1_ = (&tx1.x)[k], ty1_ = (&ty1.x)[k];
            float ta_  = (&ta.x)[k];
            int   lb   = (&lab.x)[k];

            float cbbox = fabsf(p0.x - tcx_) + fabsf(p0.y - tcy_) +
                          fabsf(p0.z - tw_ ) + fabsf(p0.w - th_ );
            float ccls = clsrow[lb];

            float ix0 = fmaxf(p1.x, tx0_), iy0 = fmaxf(p1.y, ty0_);
            float ix1 = fminf(p1.z, tx1_), iy1 = fminf(p1.w, ty1_);
            float iw  = fmaxf(ix1 - ix0, 0.0f);
            float ih  = fmaxf(iy1 - iy0, 0.0f);
            float inter = iw * ih;
            float uni   = pa + ta_ - inter;
            float iou   = inter * fast_rcp(uni);

            float cx0 = fminf(p1.x, tx0_), cy0 = fminf(p1.y, ty0_);
            float cx1 = fmaxf(p1.z, tx1_), cy1 = fmaxf(p1.w, ty1_);
            float ca  = fmaxf(cx1 - cx0, 0.0f) * fmaxf(cy1 - cy0, 0.0f);
            float giou = iou - (ca - uni) * fast_rcp(ca);

            float cost = 5.0f * cbbox + 2.0f * ccls - 2.0f * giou;

            // nan_to_num(nan=1.0, posinf=1e6, neginf=-1e6)
            if (cost != cost) cost = 1.0f;
            else cost = fminf(fmaxf(cost, -1.0e6f), 1.0e6f);
            (&res.x)[k] = cost;
        }

        *(float4*)(outb + (size_t)g * 4) = res;   // coalesced 16B/lane
    }
}

extern "C" void kernel_launch(void* const* d_in, const int* in_sizes, int n_in,
                              void* d_out, int out_size, void* d_ws, size_t ws_size,
                              hipStream_t stream) {
    const float* logits  = (const float*)d_in[0];  // [B,Q,C]
    const float* pboxes  = (const float*)d_in[1];  // [B,Q,4]
    const int*   tlabels = (const int*)  d_in[2];  // [B,T]
    const float* tboxes  = (const float*)d_in[3];  // [B,T,4]
    float* out = (float*)d_out;                    // [B,Q,T]

    dim3 grid(B * (Q / QTILE));
    dim3 block(BLOCK);
    matcher_cost_kernel<<<grid, block, 0, stream>>>(logits, pboxes, tlabels, tboxes, out);
}